// Round 5
// baseline (551.421 us; speedup 1.0000x reference)
//
#include <hip/hip_runtime.h>
#include <hip/hip_bf16.h>

#define B_ 8192
#define D_ 3072
#define C_ 512
#define E_ 8

typedef float  floatx4 __attribute__((ext_vector_type(4)));
typedef __bf16 bf16x8  __attribute__((ext_vector_type(8)));
typedef __bf16 bf16x4  __attribute__((ext_vector_type(4)));

__device__ __forceinline__ bf16x4 cvt4(float4 v) {
    bf16x4 o;
    o[0] = (__bf16)v.x; o[1] = (__bf16)v.y; o[2] = (__bf16)v.z; o[3] = (__bf16)v.w;
    return o;
}

// async global->LDS, 16B per lane. LDS dest must be wave-uniform base + lane*16.
__device__ __forceinline__ void dma16(const void* g, void* l) {
    __builtin_amdgcn_global_load_lds(
        (const __attribute__((address_space(1))) unsigned int*)(uintptr_t)g,
        (__attribute__((address_space(3))) unsigned int*)(uintptr_t)l,
        16, 0, 0);
}

// ---------------- routing ----------------
__global__ void k_count(const int* __restrict__ label, int* __restrict__ counts) {
    int b = blockIdx.x * blockDim.x + threadIdx.x;
    if (b < B_) atomicAdd(&counts[label[b]], 1);
}

__global__ void k_offsets(const int* __restrict__ counts, int* __restrict__ offsets) {
    if (threadIdx.x == 0 && blockIdx.x == 0) {
        int s = 0;
        for (int e = 0; e < E_; ++e) { offsets[e] = s; s += counts[e]; }
    }
}

__global__ void k_scatter(const int* __restrict__ label, const int* __restrict__ offsets,
                          int* __restrict__ cursors, int* __restrict__ row_ids) {
    int b = blockIdx.x * blockDim.x + threadIdx.x;
    if (b < B_) {
        int e = label[b];
        int p = atomicAdd(&cursors[e], 1);
        row_ids[offsets[e] + p] = b;
    }
}

// ---------------- prepass: fp32 -> bf16 (img gathered to sorted order, weights) ----
#define D4_ (D_ / 4)
#define NI_ (B_ * D4_)          // img float4 count
#define NW_ (E_ * C_ * D4_)     // per-weight float4 count
__global__ __launch_bounds__(256)
void k_prep(const float4* __restrict__ img4, const int* __restrict__ row_ids,
            const float4* __restrict__ We4, const float4* __restrict__ Wd4,
            bf16x4* __restrict__ imgG4, bf16x4* __restrict__ We16_4,
            bf16x4* __restrict__ Wd16_4)
{
    int i = blockIdx.x * 256 + threadIdx.x;
    const int stride = gridDim.x * 256;
    const int total = NI_ + 2 * NW_;
    for (; i < total; i += stride) {
        if (i < NI_) {
            int row = i / D4_;
            int c   = i - row * D4_;
            float4 v = img4[(size_t)row_ids[row] * D4_ + c];
            imgG4[i] = cvt4(v);
        } else if (i < NI_ + NW_) {
            int j = i - NI_;
            We16_4[j] = cvt4(We4[j]);
        } else {
            int j = i - NI_ - NW_;
            Wd16_4[j] = cvt4(Wd4[j]);
        }
    }
}

// =====================================================================
// enc: code = relu(imgG @ We16^T + benc)
// 64x128 tile, BK=32, 256 thr = 4 waves (2Mx2N), wave-tile 32x64.
// 4-buffer LDS (48 KB), d=3, vmcnt(6). XCD-aware bijective swizzle:
// nwg=512 per expert, chunk=64 (half an n-column): We-tile (768KB) hot in
// the XCD's L2 across its 64 blocks.
// =====================================================================
__global__ __launch_bounds__(256, 3)
void enc_kernel(const __bf16* __restrict__ imgG, const __bf16* __restrict__ We16,
                const float* __restrict__ benc, const int* __restrict__ counts,
                const int* __restrict__ offsets, __bf16* __restrict__ code)
{
    const int e   = blockIdx.z;
    const int cnt = counts[e];
    // XCD swizzle (nwg = 4*128 = 512, %8==0 -> xcd = bid%8; bijective)
    const int bid = blockIdx.y * gridDim.x + blockIdx.x;
    const int swz = (bid & 7) * 64 + (bid >> 3);
    const int m0  = (swz & 127) * 64;    // m-fastest within chunk
    const int n0  = (swz >> 7) * 128;
    if (m0 >= cnt) return;
    const int off = offsets[e];

    __shared__ __align__(16) __bf16 As[4][64][32];    // 16 KB
    __shared__ __align__(16) __bf16 Bs[4][128][32];   // 32 KB

    const int tid  = threadIdx.x;
    const int lane = tid & 63;
    const int wave = tid >> 6;    // 0..3
    const int wm   = wave >> 1;
    const int wn   = wave & 1;

    // DMA: row = tid>>2 (0..63), phys granule = tid&3; source col pre-swizzled.
    const int drow = tid >> 2;
    const int gsw  = (((tid & 3) ^ ((tid >> 3) & 3)) << 3);  // elems
    const __bf16* ag0 = imgG + (size_t)(off + m0 + drow) * D_ + gsw;
    const __bf16* bg0 = We16 + ((size_t)e * C_ + n0 + drow) * D_ + gsw;
    const __bf16* bg1 = bg0 + (size_t)64 * D_;
    char* lA = (char*)As + tid * 16;
    char* lB = (char*)Bs + tid * 16;

#define STG(buf, step) do {                                  \
        const size_t ko_ = (size_t)(step) * 32;              \
        dma16(ag0 + ko_, lA + (buf) * 4096);                 \
        dma16(bg0 + ko_, lB + (buf) * 8192);                 \
        dma16(bg1 + ko_, lB + (buf) * 8192 + 4096);          \
    } while (0)

    STG(0, 0);
    STG(1, 1);
    STG(2, 2);

    floatx4 acc[2][4];
    #pragma unroll
    for (int i = 0; i < 2; ++i)
        #pragma unroll
        for (int j = 0; j < 4; ++j)
            acc[i][j] = (floatx4){0.f, 0.f, 0.f, 0.f};

    const int fr = lane & 15;
    const int g4 = lane >> 4;                       // 0..3, logical k-granule
    const int psw = ((g4 ^ ((fr >> 1) & 3)) << 4);  // physical granule byte offset
    const char* Ab = (const char*)As + (wm * 32 + fr) * 64 + psw;
    const char* Bb = (const char*)Bs + (wn * 64 + fr) * 64 + psw;

    const int NS = D_ / 32;   // 96
    #pragma unroll 4
    for (int s = 0; s < NS; ++s) {
        asm volatile("s_waitcnt vmcnt(6)" ::: "memory");    // stage s complete (s+1,s+2 in flight)
        __builtin_amdgcn_s_barrier();
        asm volatile("" ::: "memory");
        __builtin_amdgcn_sched_barrier(0);
        const int ps = (s + 3 < NS) ? (s + 3) : (NS - 1);   // clamp keeps vmcnt uniform
        STG((s + 3) & 3, ps);
        const char* pA = Ab + (s & 3) * 4096;
        const char* pB = Bb + (s & 3) * 8192;
        bf16x8 af[2], bq[4];
        #pragma unroll
        for (int i = 0; i < 2; ++i) af[i] = *(const bf16x8*)(pA + i * 1024);
        #pragma unroll
        for (int j = 0; j < 4; ++j) bq[j] = *(const bf16x8*)(pB + j * 1024);
        __builtin_amdgcn_s_setprio(1);
        #pragma unroll
        for (int mt = 0; mt < 2; ++mt)
            #pragma unroll
            for (int nt = 0; nt < 4; ++nt)
                acc[mt][nt] = __builtin_amdgcn_mfma_f32_16x16x32_bf16(af[mt], bq[nt], acc[mt][nt], 0, 0, 0);
        __builtin_amdgcn_s_setprio(0);
    }
#undef STG
    asm volatile("s_waitcnt vmcnt(0)" ::: "memory");   // drain clamped tail DMAs before LDS retire

    const int rq = g4 << 2;
    #pragma unroll
    for (int nt = 0; nt < 4; ++nt) {
        const int gcol = n0 + wn * 64 + nt * 16 + fr;
        const float bias = benc[e * C_ + gcol];
        #pragma unroll
        for (int mt = 0; mt < 2; ++mt)
            #pragma unroll
            for (int reg = 0; reg < 4; ++reg) {
                const int g = m0 + wm * 32 + mt * 16 + rq + reg;
                if (g < cnt) {
                    float v = acc[mt][nt][reg] + bias;
                    v = v > 0.f ? v : 0.f;
                    code[(size_t)(off + g) * C_ + gcol] = (__bf16)v;
                }
            }
    }
}

// =====================================================================
// dec: dec = code @ Wd16^T + bdec, scatter to original rows + fused loss.
// 128x64 tile (BMxBN), BK=32, 2-buffer LDS (24 KB) -> 6 blocks/CU: per-step
// vmcnt(0) stalls hidden by 6-way block interleave; epilogue (scattered
// 100 MB stores + 50 MB imgG loads) gets 6-way overlap too.
// XCD swizzle: nwg=3072, chunk=384 (6 n-tiles x all m): Wd-chunk 384KB hot.
// =====================================================================
__global__ __launch_bounds__(256, 6)
void dec_kernel(const __bf16* __restrict__ imgG, const __bf16* __restrict__ Wd16,
                const float* __restrict__ bdec, const int* __restrict__ row_ids,
                const int* __restrict__ counts, const int* __restrict__ offsets,
                const __bf16* __restrict__ code, float* __restrict__ decoded,
                double* __restrict__ loss_acc)
{
    const int e   = blockIdx.z;
    const int cnt = counts[e];
    // XCD swizzle (nwg = 48*64 = 3072, %8==0; bijective; m-fastest in chunk)
    const int bid = blockIdx.y * gridDim.x + blockIdx.x;
    const int swz = (bid & 7) * 384 + (bid >> 3);
    const int m0  = (swz & 63) * 128;
    const int n0  = (swz >> 6) * 64;
    if (m0 >= cnt) return;
    const int off = offsets[e];

    __shared__ __align__(16) __bf16 As[2][128][32];   // 16 KB
    __shared__ __align__(16) __bf16 Bs[2][64][32];    // 8 KB
    __shared__ float red[4];

    const int tid  = threadIdx.x;
    const int lane = tid & 63;
    const int wave = tid >> 6;
    const int wm   = wave >> 1;
    const int wn   = wave & 1;

    const int drow = tid >> 2;
    const int gsw  = (((tid & 3) ^ ((tid >> 3) & 3)) << 3);
    const __bf16* ag0 = code + (size_t)(off + m0 + drow) * C_ + gsw;
    const __bf16* ag1 = ag0 + (size_t)64 * C_;
    const __bf16* bg0 = Wd16 + ((size_t)e * D_ + n0 + drow) * C_ + gsw;
    char* lA = (char*)As + tid * 16;
    char* lB = (char*)Bs + tid * 16;

#define STG(buf, step) do {                                  \
        const size_t ko_ = (size_t)(step) * 32;              \
        dma16(ag0 + ko_, lA + (buf) * 8192);                 \
        dma16(ag1 + ko_, lA + (buf) * 8192 + 4096);          \
        dma16(bg0 + ko_, lB + (buf) * 4096);                 \
    } while (0)

    STG(0, 0);

    floatx4 acc[4][2];
    #pragma unroll
    for (int i = 0; i < 4; ++i)
        #pragma unroll
        for (int j = 0; j < 2; ++j)
            acc[i][j] = (floatx4){0.f, 0.f, 0.f, 0.f};

    const int fr = lane & 15;
    const int g4 = lane >> 4;
    const int psw = ((g4 ^ ((fr >> 1) & 3)) << 4);
    const char* Ab = (const char*)As + (wm * 64 + fr) * 64 + psw;
    const char* Bb = (const char*)Bs + (wn * 32 + fr) * 64 + psw;

    const int NS = C_ / 32;   // 16
    #pragma unroll 4
    for (int s = 0; s < NS; ++s) {
        asm volatile("s_waitcnt vmcnt(0)" ::: "memory");    // own stage-s DMAs done
        __builtin_amdgcn_s_barrier();                       // all waves' DMAs + buf(s-1) reads done
        asm volatile("" ::: "memory");
        __builtin_amdgcn_sched_barrier(0);
        if (s + 1 < NS) STG((s + 1) & 1, s + 1);
        const char* pA = Ab + (s & 1) * 8192;
        const char* pB = Bb + (s & 1) * 4096;
        bf16x8 af[4], bq[2];
        #pragma unroll
        for (int i = 0; i < 4; ++i) af[i] = *(const bf16x8*)(pA + i * 1024);
        #pragma unroll
        for (int j = 0; j < 2; ++j) bq[j] = *(const bf16x8*)(pB + j * 1024);
        __builtin_amdgcn_s_setprio(1);
        #pragma unroll
        for (int mt = 0; mt < 4; ++mt)
            #pragma unroll
            for (int nt = 0; nt < 2; ++nt)
                acc[mt][nt] = __builtin_amdgcn_mfma_f32_16x16x32_bf16(af[mt], bq[nt], acc[mt][nt], 0, 0, 0);
        __builtin_amdgcn_s_setprio(0);
    }
#undef STG

    const int rq = g4 << 2;
    int orig[4][4];
    #pragma unroll
    for (int mt = 0; mt < 4; ++mt)
        #pragma unroll
        for (int reg = 0; reg < 4; ++reg) {
            const int g = m0 + wm * 64 + mt * 16 + rq + reg;
            orig[mt][reg] = (g < cnt) ? row_ids[off + g] : -1;
        }

    float lsum = 0.f;
    #pragma unroll
    for (int nt = 0; nt < 2; ++nt) {
        const int gcol = n0 + wn * 32 + nt * 16 + fr;
        const float bias = bdec[e * D_ + gcol];
        #pragma unroll
        for (int mt = 0; mt < 4; ++mt)
            #pragma unroll
            for (int reg = 0; reg < 4; ++reg) {
                if (orig[mt][reg] >= 0) {
                    const int g = m0 + wm * 64 + mt * 16 + rq + reg;
                    float v = acc[mt][nt][reg] + bias;
                    decoded[(size_t)orig[mt][reg] * D_ + gcol] = v;
                    float d = v - (float)imgG[(size_t)(off + g) * D_ + gcol];
                    lsum += d * d;
                }
            }
    }
    #pragma unroll
    for (int o = 32; o > 0; o >>= 1) lsum += __shfl_down(lsum, o, 64);
    if (lane == 0) red[wave] = lsum;
    __syncthreads();
    if (tid == 0) atomicAdd(loss_acc, (double)(red[0] + red[1] + red[2] + red[3]));
}

__global__ void k_final(const double* __restrict__ loss_acc, float* __restrict__ out) {
    if (threadIdx.x == 0 && blockIdx.x == 0)
        out[0] = (float)(*loss_acc / (double)((size_t)B_ * (size_t)D_));
}

// ---------------- launch ----------------
extern "C" void kernel_launch(void* const* d_in, const int* in_sizes, int n_in,
                              void* d_out, int out_size, void* d_ws, size_t ws_size,
                              hipStream_t stream)
{
    const float* img   = (const float*)d_in[0];
    const int*   label = (const int*)d_in[1];
    const float* Wenc  = (const float*)d_in[2];
    const float* benc  = (const float*)d_in[3];
    const float* Wdec  = (const float*)d_in[4];
    const float* bdec  = (const float*)d_in[5];
    float* out = (float*)d_out;

    char* ws = (char*)d_ws;
    int*    counts  = (int*)(ws + 0);
    int*    cursors = (int*)(ws + 32);
    int*    offsets = (int*)(ws + 64);
    double* loss    = (double*)(ws + 96);
    int*    row_ids = (int*)(ws + 128);
    // bf16 scratch (sizes include 128 rows of tail slack for OOB tile reads):
    __bf16* code = (__bf16*)(ws + 65536);                               // (B+128)*C*2 = 8,519,680
    __bf16* imgG = (__bf16*)(ws + 65536 + 8519680);                     // (B+128)*D*2 = 51,118,080
    __bf16* We16 = (__bf16*)(ws + 65536 + 8519680 + 51118080);          // E*C*D*2 = 25,165,824
    __bf16* Wd16 = (__bf16*)(ws + 65536 + 8519680 + 51118080 + 25165824);
    // total ws use ~105 MB

    hipMemsetAsync(d_ws, 0, 128, stream);
    k_count  <<<dim3(B_ / 256), dim3(256), 0, stream>>>(label, counts);
    k_offsets<<<dim3(1),        dim3(64),  0, stream>>>(counts, offsets);
    k_scatter<<<dim3(B_ / 256), dim3(256), 0, stream>>>(label, offsets, cursors, row_ids);
    k_prep   <<<dim3(2048),     dim3(256), 0, stream>>>(
        (const float4*)img, row_ids, (const float4*)Wenc, (const float4*)Wdec,
        (bf16x4*)imgG, (bf16x4*)We16, (bf16x4*)Wd16);
    enc_kernel<<<dim3(C_ / 128, B_ / 64, E_), dim3(256), 0, stream>>>(
        imgG, We16, benc, counts, offsets, code);
    dec_kernel<<<dim3(D_ / 64, B_ / 128, E_), dim3(256), 0, stream>>>(
        imgG, Wd16, bdec, row_ids, counts, offsets, code, out + 1, loss);
    k_final<<<dim3(1), dim3(64), 0, stream>>>(loss, out);
}

// Round 6
// 445.521 us; speedup vs baseline: 1.2377x; 1.2377x over previous
//
#include <hip/hip_runtime.h>
#include <hip/hip_bf16.h>

#define B_ 8192
#define D_ 3072
#define C_ 512
#define E_ 8
#define MAXTILES_ 136   // sum ceil(cnt/64) <= 128+7; grid padded to 136

typedef float  floatx4 __attribute__((ext_vector_type(4)));
typedef __bf16 bf16x8  __attribute__((ext_vector_type(8)));
typedef __bf16 bf16x4  __attribute__((ext_vector_type(4)));

__device__ __forceinline__ bf16x4 cvt4(float4 v) {
    bf16x4 o;
    o[0] = (__bf16)v.x; o[1] = (__bf16)v.y; o[2] = (__bf16)v.z; o[3] = (__bf16)v.w;
    return o;
}

// async global->LDS, 16B per lane. LDS dest must be wave-uniform base + lane*16.
__device__ __forceinline__ void dma16(const void* g, void* l) {
    __builtin_amdgcn_global_load_lds(
        (const __attribute__((address_space(1))) unsigned int*)(uintptr_t)g,
        (__attribute__((address_space(3))) unsigned int*)(uintptr_t)l,
        16, 0, 0);
}

// ---------------- fused routing: count + offsets + tile table + scatter ------
// Single block, 1024 threads. LDS counters (8 experts). Also zeros loss.
__global__ __launch_bounds__(1024)
void k_route(const int* __restrict__ label, int* __restrict__ counts,
             int* __restrict__ offsets, int* __restrict__ row_ids,
             int* __restrict__ tile_e, int* __restrict__ tile_m,
             int* __restrict__ ntiles, double* __restrict__ loss)
{
    __shared__ int cnt_s[E_], off_s[E_], cur_s[E_];
    const int tid = threadIdx.x;
    if (tid < E_) cnt_s[tid] = 0;
    __syncthreads();
    for (int b = tid; b < B_; b += 1024) atomicAdd(&cnt_s[label[b]], 1);
    __syncthreads();
    if (tid == 0) {
        int s = 0, t = 0;
        for (int e = 0; e < E_; ++e) {
            off_s[e] = s; offsets[e] = s; counts[e] = cnt_s[e]; cur_s[e] = 0;
            for (int m = 0; m < cnt_s[e]; m += 64) { tile_e[t] = e; tile_m[t] = m; ++t; }
            s += cnt_s[e];
        }
        *ntiles = t;
        *loss = 0.0;
    }
    __syncthreads();
    for (int b = tid; b < B_; b += 1024) {
        int e = label[b];
        int p = atomicAdd(&cur_s[e], 1);
        row_ids[off_s[e] + p] = b;
    }
}

// ---------------- prepass: fp32 -> bf16 (img gathered to sorted order, weights) ----
#define D4_ (D_ / 4)
#define NI_ (B_ * D4_)          // img float4 count
#define NW_ (E_ * C_ * D4_)     // per-weight float4 count
__global__ __launch_bounds__(256)
void k_prep(const float4* __restrict__ img4, const int* __restrict__ row_ids,
            const float4* __restrict__ We4, const float4* __restrict__ Wd4,
            bf16x4* __restrict__ imgG4, bf16x4* __restrict__ We16_4,
            bf16x4* __restrict__ Wd16_4)
{
    int i = blockIdx.x * 256 + threadIdx.x;
    const int stride = gridDim.x * 256;
    const int total = NI_ + 2 * NW_;
    for (; i < total; i += stride) {
        if (i < NI_) {
            int row = i / D4_;
            int c   = i - row * D4_;
            float4 v = img4[(size_t)row_ids[row] * D4_ + c];
            imgG4[i] = cvt4(v);
        } else if (i < NI_ + NW_) {
            int j = i - NI_;
            We16_4[j] = cvt4(We4[j]);
        } else {
            int j = i - NI_ - NW_;
            Wd16_4[j] = cvt4(Wd4[j]);
        }
    }
}

// =====================================================================
// enc: code = relu(imgG @ We16^T + benc)
// Flattened grid over a dense tile table (all m-tiles working): grid =
// 4 n-tiles x 136 m-slots = 544 blocks. Bijective XCD swizzle (544=8x68,
// m-fastest): every XCD gets 68 working tiles; its We n-panels (~3MB) L2-hot.
// 64x128 tile, BK=32, 4 waves (2Mx2N), wave-tile 32x64; 4-buffer LDS (48KB),
// d=3, vmcnt(6), one s_barrier per step.
// =====================================================================
__global__ __launch_bounds__(256, 3)
void enc_kernel(const __bf16* __restrict__ imgG, const __bf16* __restrict__ We16,
                const float* __restrict__ benc, const int* __restrict__ counts,
                const int* __restrict__ offsets, const int* __restrict__ tile_e,
                const int* __restrict__ tile_m, const int* __restrict__ ntiles,
                __bf16* __restrict__ code)
{
    const int bid = blockIdx.y * gridDim.x + blockIdx.x;   // [0,544)
    const int swz = (bid & 7) * 68 + (bid >> 3);           // bijective, 544=8*68
    const int t   = swz % MAXTILES_;                       // m-tile slot (fastest)
    const int n0  = (swz / MAXTILES_) * 128;
    if (t >= *ntiles) return;                              // <=7 dead blocks, balanced
    const int e   = tile_e[t];
    const int m0  = tile_m[t];
    const int cnt = counts[e];
    const int off = offsets[e];

    __shared__ __align__(16) __bf16 As[4][64][32];    // 16 KB
    __shared__ __align__(16) __bf16 Bs[4][128][32];   // 32 KB

    const int tid  = threadIdx.x;
    const int lane = tid & 63;
    const int wave = tid >> 6;    // 0..3
    const int wm   = wave >> 1;
    const int wn   = wave & 1;

    // DMA: row = tid>>2 (0..63), phys granule = tid&3; source col pre-swizzled.
    const int drow = tid >> 2;
    const int gsw  = (((tid & 3) ^ ((tid >> 3) & 3)) << 3);  // elems
    const __bf16* ag0 = imgG + (size_t)(off + m0 + drow) * D_ + gsw;
    const __bf16* bg0 = We16 + ((size_t)e * C_ + n0 + drow) * D_ + gsw;
    const __bf16* bg1 = bg0 + (size_t)64 * D_;
    char* lA = (char*)As + tid * 16;
    char* lB = (char*)Bs + tid * 16;

#define STG(buf, step) do {                                  \
        const size_t ko_ = (size_t)(step) * 32;              \
        dma16(ag0 + ko_, lA + (buf) * 4096);                 \
        dma16(bg0 + ko_, lB + (buf) * 8192);                 \
        dma16(bg1 + ko_, lB + (buf) * 8192 + 4096);          \
    } while (0)

    STG(0, 0);
    STG(1, 1);
    STG(2, 2);

    floatx4 acc[2][4];
    #pragma unroll
    for (int i = 0; i < 2; ++i)
        #pragma unroll
        for (int j = 0; j < 4; ++j)
            acc[i][j] = (floatx4){0.f, 0.f, 0.f, 0.f};

    const int fr = lane & 15;
    const int g4 = lane >> 4;                       // 0..3, logical k-granule
    const int psw = ((g4 ^ ((fr >> 1) & 3)) << 4);  // physical granule byte offset
    const char* Ab = (const char*)As + (wm * 32 + fr) * 64 + psw;
    const char* Bb = (const char*)Bs + (wn * 64 + fr) * 64 + psw;

    const int NS = D_ / 32;   // 96
    #pragma unroll 4
    for (int s = 0; s < NS; ++s) {
        asm volatile("s_waitcnt vmcnt(6)" ::: "memory");    // stage s complete (s+1,s+2 in flight)
        __builtin_amdgcn_s_barrier();
        asm volatile("" ::: "memory");
        __builtin_amdgcn_sched_barrier(0);
        const int ps = (s + 3 < NS) ? (s + 3) : (NS - 1);   // clamp keeps vmcnt uniform
        STG((s + 3) & 3, ps);
        const char* pA = Ab + (s & 3) * 4096;
        const char* pB = Bb + (s & 3) * 8192;
        bf16x8 af[2], bq[4];
        #pragma unroll
        for (int i = 0; i < 2; ++i) af[i] = *(const bf16x8*)(pA + i * 1024);
        #pragma unroll
        for (int j = 0; j < 4; ++j) bq[j] = *(const bf16x8*)(pB + j * 1024);
        __builtin_amdgcn_s_setprio(1);
        #pragma unroll
        for (int mt = 0; mt < 2; ++mt)
            #pragma unroll
            for (int nt = 0; nt < 4; ++nt)
                acc[mt][nt] = __builtin_amdgcn_mfma_f32_16x16x32_bf16(af[mt], bq[nt], acc[mt][nt], 0, 0, 0);
        __builtin_amdgcn_s_setprio(0);
    }
#undef STG
    asm volatile("s_waitcnt vmcnt(0)" ::: "memory");   // drain clamped tail DMAs before LDS retire

    const int rq = g4 << 2;
    #pragma unroll
    for (int nt = 0; nt < 4; ++nt) {
        const int gcol = n0 + wn * 64 + nt * 16 + fr;
        const float bias = benc[e * C_ + gcol];
        #pragma unroll
        for (int mt = 0; mt < 2; ++mt)
            #pragma unroll
            for (int reg = 0; reg < 4; ++reg) {
                const int g = m0 + wm * 32 + mt * 16 + rq + reg;
                if (g < cnt) {
                    float v = acc[mt][nt][reg] + bias;
                    v = v > 0.f ? v : 0.f;
                    code[(size_t)(off + g) * C_ + gcol] = (__bf16)v;
                }
            }
    }
}

// =====================================================================
// dec: dec = code @ Wd16^T + bdec, scatter to original rows + fused loss.
// 128x64 tile (BMxBN), BK=32, 2-buffer LDS (24 KB) -> 6 blocks/CU: per-step
// vmcnt(0) stalls hidden by 6-way block interleave; epilogue (scattered
// 100 MB stores + 50 MB imgG loads) gets 6-way overlap too.
// XCD swizzle: nwg=3072, chunk=384 (6 n-tiles x all m): Wd-chunk hot,
// balanced (chunks span complete m-ranges).
// =====================================================================
__global__ __launch_bounds__(256, 6)
void dec_kernel(const __bf16* __restrict__ imgG, const __bf16* __restrict__ Wd16,
                const float* __restrict__ bdec, const int* __restrict__ row_ids,
                const int* __restrict__ counts, const int* __restrict__ offsets,
                const __bf16* __restrict__ code, float* __restrict__ decoded,
                double* __restrict__ loss_acc)
{
    const int e   = blockIdx.z;
    const int cnt = counts[e];
    // XCD swizzle (nwg = 48*64 = 3072, %8==0; bijective; m-fastest in chunk)
    const int bid = blockIdx.y * gridDim.x + blockIdx.x;
    const int swz = (bid & 7) * 384 + (bid >> 3);
    const int m0  = (swz & 63) * 128;
    const int n0  = (swz >> 6) * 64;
    if (m0 >= cnt) return;
    const int off = offsets[e];

    __shared__ __align__(16) __bf16 As[2][128][32];   // 16 KB
    __shared__ __align__(16) __bf16 Bs[2][64][32];    // 8 KB
    __shared__ float red[4];

    const int tid  = threadIdx.x;
    const int lane = tid & 63;
    const int wave = tid >> 6;
    const int wm   = wave >> 1;
    const int wn   = wave & 1;

    const int drow = tid >> 2;
    const int gsw  = (((tid & 3) ^ ((tid >> 3) & 3)) << 3);
    const __bf16* ag0 = code + (size_t)(off + m0 + drow) * C_ + gsw;
    const __bf16* ag1 = ag0 + (size_t)64 * C_;
    const __bf16* bg0 = Wd16 + ((size_t)e * D_ + n0 + drow) * C_ + gsw;
    char* lA = (char*)As + tid * 16;
    char* lB = (char*)Bs + tid * 16;

#define STG(buf, step) do {                                  \
        const size_t ko_ = (size_t)(step) * 32;              \
        dma16(ag0 + ko_, lA + (buf) * 8192);                 \
        dma16(ag1 + ko_, lA + (buf) * 8192 + 4096);          \
        dma16(bg0 + ko_, lB + (buf) * 4096);                 \
    } while (0)

    STG(0, 0);

    floatx4 acc[4][2];
    #pragma unroll
    for (int i = 0; i < 4; ++i)
        #pragma unroll
        for (int j = 0; j < 2; ++j)
            acc[i][j] = (floatx4){0.f, 0.f, 0.f, 0.f};

    const int fr = lane & 15;
    const int g4 = lane >> 4;
    const int psw = ((g4 ^ ((fr >> 1) & 3)) << 4);
    const char* Ab = (const char*)As + (wm * 64 + fr) * 64 + psw;
    const char* Bb = (const char*)Bs + (wn * 32 + fr) * 64 + psw;

    const int NS = C_ / 32;   // 16
    #pragma unroll 4
    for (int s = 0; s < NS; ++s) {
        asm volatile("s_waitcnt vmcnt(0)" ::: "memory");    // own stage-s DMAs done
        __builtin_amdgcn_s_barrier();                       // all waves' DMAs + buf(s-1) reads done
        asm volatile("" ::: "memory");
        __builtin_amdgcn_sched_barrier(0);
        if (s + 1 < NS) STG((s + 1) & 1, s + 1);
        const char* pA = Ab + (s & 1) * 8192;
        const char* pB = Bb + (s & 1) * 4096;
        bf16x8 af[4], bq[2];
        #pragma unroll
        for (int i = 0; i < 4; ++i) af[i] = *(const bf16x8*)(pA + i * 1024);
        #pragma unroll
        for (int j = 0; j < 2; ++j) bq[j] = *(const bf16x8*)(pB + j * 1024);
        __builtin_amdgcn_s_setprio(1);
        #pragma unroll
        for (int mt = 0; mt < 4; ++mt)
            #pragma unroll
            for (int nt = 0; nt < 2; ++nt)
                acc[mt][nt] = __builtin_amdgcn_mfma_f32_16x16x32_bf16(af[mt], bq[nt], acc[mt][nt], 0, 0, 0);
        __builtin_amdgcn_s_setprio(0);
    }
#undef STG

    const int rq = g4 << 2;
    int orig[4][4];
    #pragma unroll
    for (int mt = 0; mt < 4; ++mt)
        #pragma unroll
        for (int reg = 0; reg < 4; ++reg) {
            const int g = m0 + wm * 64 + mt * 16 + rq + reg;
            orig[mt][reg] = (g < cnt) ? row_ids[off + g] : -1;
        }

    float lsum = 0.f;
    #pragma unroll
    for (int nt = 0; nt < 2; ++nt) {
        const int gcol = n0 + wn * 32 + nt * 16 + fr;
        const float bias = bdec[e * D_ + gcol];
        #pragma unroll
        for (int mt = 0; mt < 4; ++mt)
            #pragma unroll
            for (int reg = 0; reg < 4; ++reg) {
                if (orig[mt][reg] >= 0) {
                    const int g = m0 + wm * 64 + mt * 16 + rq + reg;
                    float v = acc[mt][nt][reg] + bias;
                    decoded[(size_t)orig[mt][reg] * D_ + gcol] = v;
                    float d = v - (float)imgG[(size_t)(off + g) * D_ + gcol];
                    lsum += d * d;
                }
            }
    }
    #pragma unroll
    for (int o = 32; o > 0; o >>= 1) lsum += __shfl_down(lsum, o, 64);
    if (lane == 0) red[wave] = lsum;
    __syncthreads();
    if (tid == 0) atomicAdd(loss_acc, (double)(red[0] + red[1] + red[2] + red[3]));
}

__global__ void k_final(const double* __restrict__ loss_acc, float* __restrict__ out) {
    if (threadIdx.x == 0 && blockIdx.x == 0)
        out[0] = (float)(*loss_acc / (double)((size_t)B_ * (size_t)D_));
}

// ---------------- launch ----------------
extern "C" void kernel_launch(void* const* d_in, const int* in_sizes, int n_in,
                              void* d_out, int out_size, void* d_ws, size_t ws_size,
                              hipStream_t stream)
{
    const float* img   = (const float*)d_in[0];
    const int*   label = (const int*)d_in[1];
    const float* Wenc  = (const float*)d_in[2];
    const float* benc  = (const float*)d_in[3];
    const float* Wdec  = (const float*)d_in[4];
    const float* bdec  = (const float*)d_in[5];
    float* out = (float*)d_out;

    char* ws = (char*)d_ws;
    int*    counts  = (int*)(ws + 0);
    int*    offsets = (int*)(ws + 64);
    double* loss    = (double*)(ws + 96);
    int*    row_ids = (int*)(ws + 128);          // B_*4 = 32768 -> ends 32896
    int*    tile_e  = (int*)(ws + 40960);        // 136*4
    int*    tile_m  = (int*)(ws + 41984);
    int*    ntiles  = (int*)(ws + 43008);
    // bf16 scratch (sizes include 128 rows of tail slack for OOB tile reads):
    __bf16* code = (__bf16*)(ws + 65536);                               // (B+128)*C*2 = 8,519,680
    __bf16* imgG = (__bf16*)(ws + 65536 + 8519680);                     // (B+128)*D*2 = 51,118,080
    __bf16* We16 = (__bf16*)(ws + 65536 + 8519680 + 51118080);          // E*C*D*2 = 25,165,824
    __bf16* Wd16 = (__bf16*)(ws + 65536 + 8519680 + 51118080 + 25165824);
    // total ws use ~105 MB

    k_route<<<dim3(1), dim3(1024), 0, stream>>>(
        label, counts, offsets, row_ids, tile_e, tile_m, ntiles, loss);
    k_prep <<<dim3(2048), dim3(256), 0, stream>>>(
        (const float4*)img, row_ids, (const float4*)Wenc, (const float4*)Wdec,
        (bf16x4*)imgG, (bf16x4*)We16, (bf16x4*)Wd16);
    enc_kernel<<<dim3(C_ / 128, MAXTILES_, 1), dim3(256), 0, stream>>>(
        imgG, We16, benc, counts, offsets, tile_e, tile_m, ntiles, code);
    dec_kernel<<<dim3(D_ / 64, B_ / 128, E_), dim3(256), 0, stream>>>(
        imgG, Wd16, bdec, row_ids, counts, offsets, code, out + 1, loss);
    k_final<<<dim3(1), dim3(64), 0, stream>>>(loss, out);
}